// Round 1
// baseline (143.722 us; speedup 1.0000x reference)
//
#include <hip/hip_runtime.h>
#include <hip/hip_bf16.h>
#include <float.h>

// VQ-VAE quantization for x:[8,64,32,32,32] f32, embedding:[512,64] f32.
// Outputs (flat, f32): [0] loss, [1..16777216] quantized [B,C,D,H,W], [16777217] perplexity.

#define EDIM      64
#define NCODES    512
#define SPATIAL   32768        // 32*32*32
#define OUT_ELEMS 16777216     // 8*64*32768
#define NROWS     262144       // 8*32768

typedef __attribute__((ext_vector_type(8))) short  short8;
typedef __attribute__((ext_vector_type(4))) short  short4v;
typedef __attribute__((ext_vector_type(4))) float  float4v;

static __device__ __forceinline__ short f32_to_bf16_bits(float f) {
    union { float f; unsigned u; } v; v.f = f;
    unsigned r = v.u + 0x7FFFu + ((v.u >> 16) & 1u);   // RNE, no NaN inputs
    return (short)(r >> 16);
}

// ---------------- prep: bf16(-2*e) table, exact |e|^2, zero accumulators ----
__global__ void vq_prep(const float* __restrict__ emb,
                        float* __restrict__ loss_acc,
                        unsigned* __restrict__ counts,
                        float* __restrict__ eNorm,
                        short* __restrict__ ebf) {
    int j = blockIdx.x;        // 512 blocks
    int c = threadIdx.x;       // 64 threads = 1 wave
    float v = emb[j * EDIM + c];
    ebf[j * EDIM + c] = f32_to_bf16_bits(-2.0f * v);
    float sq = v * v;
    #pragma unroll
    for (int m = 32; m; m >>= 1) sq += __shfl_xor(sq, m, 64);
    if (c == 0) {
        eNorm[j]  = sq;
        counts[j] = 0u;
        if (j == 0) *loss_acc = 0.0f;
    }
}

// ---------------- main: distances via MFMA, argmin, quantized write ---------
__global__ __launch_bounds__(256) void vq_main(
        const float* __restrict__ x,
        const float* __restrict__ emb,
        const float* __restrict__ eNorm,
        const short* __restrict__ ebf,
        float* __restrict__ out,
        float* __restrict__ loss_acc,
        unsigned* __restrict__ counts) {

    __shared__ unsigned short idx_lds[256];
    __shared__ float          red4[4];
    __shared__ short          stage[256 * 68];   // 256 s-rows x 64 c, pad to 68 (34.8 KB)

    const int tid  = threadIdx.x;
    const int wave = tid >> 6;
    const int lane = tid & 63;
    const int lrow = lane & 15;    // A-row / B-col / D-col lane field
    const int lk   = lane >> 4;    // k-chunk / D-row-group lane field
    const int blk  = blockIdx.x;
    const int b    = blk >> 7;           // 128 blocks per batch
    const int s0   = (blk & 127) << 8;   // 256 spatial positions per block
    const long xbase = ((long)b << 21);  // b*64*32768

    // ---- A fragments: 4 row-tiles x 2 k-chunks; accumulate sum(x^2) --------
    float  x2 = 0.0f;
    short8 afr[4][2];
    #pragma unroll
    for (int r = 0; r < 4; ++r) {
        const int s = s0 + wave * 64 + r * 16 + lrow;
        #pragma unroll
        for (int kk = 0; kk < 2; ++kk) {
            const float* xp = x + xbase + ((long)(kk * 32 + lk * 8) << 15) + s;
            #pragma unroll
            for (int i = 0; i < 8; ++i) {
                float v = xp[(long)i << 15];
                x2 += v * v;
                afr[r][kk][i] = f32_to_bf16_bits(v);
            }
        }
    }

    // ---- scan all 512 codes in 16-code tiles -------------------------------
    float minv[4][4];
    int   mini[4][4];
    #pragma unroll
    for (int r = 0; r < 4; ++r)
        #pragma unroll
        for (int q = 0; q < 4; ++q) { minv[r][q] = FLT_MAX; mini[r][q] = 0; }

    const short8* ebv = (const short8*)ebf;
    for (int jt = 0; jt < 32; ++jt) {
        const int j = jt * 16 + lrow;                 // this lane's code (B col)
        short8 b0 = ebv[j * 8 + lk];                  // channels [lk*8 .. +7]
        short8 b1 = ebv[j * 8 + 4 + lk];              // channels [32+lk*8 .. +7]
        float  en = eNorm[j];
        #pragma unroll
        for (int r = 0; r < 4; ++r) {
            float4v acc = {0.f, 0.f, 0.f, 0.f};
            acc = __builtin_amdgcn_mfma_f32_16x16x32_bf16(afr[r][0], b0, acc, 0, 0, 0);
            acc = __builtin_amdgcn_mfma_f32_16x16x32_bf16(afr[r][1], b1, acc, 0, 0, 0);
            #pragma unroll
            for (int q = 0; q < 4; ++q) {
                float sv = en + acc[q];               // |e|^2 - 2 x.e
                bool lt = sv < minv[r][q];
                minv[r][q] = lt ? sv : minv[r][q];
                mini[r][q] = lt ? j  : mini[r][q];
            }
        }
    }

    // ---- argmin butterfly across the 16 code-lanes -------------------------
    #pragma unroll
    for (int r = 0; r < 4; ++r) {
        #pragma unroll
        for (int q = 0; q < 4; ++q) {
            float mv = minv[r][q]; int mi = mini[r][q];
            #pragma unroll
            for (int m = 1; m < 16; m <<= 1) {
                float ov = __shfl_xor(mv, m, 64);
                int   oi = __shfl_xor(mi, m, 64);
                bool take = (ov < mv) || (ov == mv && oi < mi);
                mv = take ? ov : mv;
                mi = take ? oi : mi;
            }
            minv[r][q] = mv; mini[r][q] = mi;
        }
    }

    // ---- per-row results: idx -> LDS, loss partial -------------------------
    float smin = 0.0f;
    if (lrow == 0) {
        #pragma unroll
        for (int r = 0; r < 4; ++r)
            #pragma unroll
            for (int q = 0; q < 4; ++q) {
                idx_lds[wave * 64 + r * 16 + lk * 4 + q] = (unsigned short)mini[r][q];
                smin += minv[r][q];
            }
    }
    float tot = x2 + smin;   // sum (q-x)^2 over this wave's rows = sum x^2 + sum s_min
    #pragma unroll
    for (int m = 32; m; m >>= 1) tot += __shfl_xor(tot, m, 64);
    if (lane == 0) red4[wave] = tot;

    __syncthreads();
    if (tid == 0) atomicAdd(loss_acc, red4[0] + red4[1] + red4[2] + red4[3]);

    // ---- histogram + stage quantized rows (bf16) for transposed write ------
    {
        const int j = idx_lds[tid];
        atomicAdd(&counts[j], 1u);
        const float4v* ep = (const float4v*)(emb + j * EDIM);
        #pragma unroll
        for (int qq = 0; qq < 16; ++qq) {
            float4v ev = ep[qq];
            short4v sv;
            sv[0] = f32_to_bf16_bits(ev[0]);
            sv[1] = f32_to_bf16_bits(ev[1]);
            sv[2] = f32_to_bf16_bits(ev[2]);
            sv[3] = f32_to_bf16_bits(ev[3]);
            *(short4v*)&stage[tid * 68 + qq * 4] = sv;
        }
    }
    __syncthreads();

    // ---- coalesced [C][S] write: lane = s, loop c --------------------------
    #pragma unroll 4
    for (int c = 0; c < 64; ++c) {
        unsigned bits = (unsigned)(unsigned short)stage[tid * 68 + c];
        out[1 + xbase + ((long)c << 15) + s0 + tid] = __uint_as_float(bits << 16);
    }
}

// ---------------- final: scalars -------------------------------------------
__global__ void vq_final(const unsigned* __restrict__ counts,
                         const float* __restrict__ loss_acc,
                         float* __restrict__ out) {
    __shared__ float red[512];
    int t = threadIdx.x;
    float p = (float)counts[t] * (1.0f / 262144.0f);
    red[t] = p * logf(p + 1e-10f);
    __syncthreads();
    for (int m = 256; m; m >>= 1) {
        if (t < m) red[t] += red[t + m];
        __syncthreads();
    }
    if (t == 0) {
        out[0]         = 1.25f * (*loss_acc) * (1.0f / 16777216.0f);
        out[1 + OUT_ELEMS] = expf(-red[0]);
    }
}

extern "C" void kernel_launch(void* const* d_in, const int* in_sizes, int n_in,
                              void* d_out, int out_size, void* d_ws, size_t ws_size,
                              hipStream_t stream) {
    const float* x   = (const float*)d_in[0];
    const float* emb = (const float*)d_in[1];
    float* out = (float*)d_out;

    char* ws = (char*)d_ws;
    float*    loss_acc = (float*)ws;              // 4 B
    unsigned* counts   = (unsigned*)(ws + 64);    // 2 KB
    float*    eNorm    = (float*)(ws + 4096);     // 2 KB
    short*    ebf      = (short*)(ws + 8192);     // 64 KB bf16(-2*e) table

    vq_prep <<<NCODES, 64, 0, stream>>>(emb, loss_acc, counts, eNorm, ebf);
    vq_main <<<1024, 256, 0, stream>>>(x, emb, eNorm, ebf, out, loss_acc, counts);
    vq_final<<<1, 512, 0, stream>>>(counts, loss_acc, out);
}

// Round 2
// 106.234 us; speedup vs baseline: 1.3529x; 1.3529x over previous
//
#include <hip/hip_runtime.h>
#include <hip/hip_bf16.h>
#include <float.h>

// VQ-VAE quantization for x:[8,64,32,32,32] f32, embedding:[512,64] f32.
// Outputs (flat, f32): [0] loss, [1..16777216] quantized [B,C,D,H,W], [16777217] perplexity.

#define EDIM      64
#define NCODES    512
#define SPATIAL   32768        // 32*32*32
#define OUT_ELEMS 16777216     // 8*64*32768
#define NROWS     262144       // 8*32768

typedef __attribute__((ext_vector_type(8))) short  short8;
typedef __attribute__((ext_vector_type(4))) float  float4v;
typedef __attribute__((ext_vector_type(4))) unsigned short ushort4v;

static __device__ __forceinline__ short f32_to_bf16_bits(float f) {
    union { float f; unsigned u; } v; v.f = f;
    unsigned r = v.u + 0x7FFFu + ((v.u >> 16) & 1u);   // RNE, no NaN inputs
    return (short)(r >> 16);
}

// ---------------- prep: bf16(-2*e) table, |e|^2 + 16 bias, zero accumulators
__global__ void vq_prep(const float* __restrict__ emb,
                        float* __restrict__ loss_acc,
                        unsigned* __restrict__ counts,
                        float* __restrict__ eNorm16,
                        short* __restrict__ ebf) {
    int j = blockIdx.x;        // 512 blocks
    int c = threadIdx.x;       // 64 threads = 1 wave
    float v = emb[j * EDIM + c];
    ebf[j * EDIM + c] = f32_to_bf16_bits(-2.0f * v);
    float sq = v * v;
    #pragma unroll
    for (int m = 32; m; m >>= 1) sq += __shfl_xor(sq, m, 64);
    if (c == 0) {
        eNorm16[j] = sq + 16.0f;     // bias so distance keys are positive floats
        counts[j]  = 0u;
        if (j == 0) *loss_acc = 0.0f;
    }
}

// ---------------- argmin: MFMA distances, key-packed min, idx + loss --------
__global__ __launch_bounds__(256) void vq_argmin(
        const float* __restrict__ x,
        const float* __restrict__ eNorm16,
        const short* __restrict__ ebf,
        unsigned short* __restrict__ idx_out,
        float* __restrict__ loss_acc) {

    __shared__ float red4[4];

    const int tid  = threadIdx.x;
    const int wave = tid >> 6;
    const int lane = tid & 63;
    const int lrow = lane & 15;    // A-row / B-col / D-col lane field
    const int lk   = lane >> 4;    // k-chunk / D-row-group lane field
    const int blk  = blockIdx.x;
    const int b    = blk >> 8;            // 256 blocks per batch
    const int s0   = (blk & 255) << 7;    // 128 rows per block
    const long xbase = ((long)b << 21);   // b*64*32768

    // ---- A fragments: 2 row-tiles x 2 k-chunks; accumulate sum(x^2) --------
    float  x2 = 0.0f;
    short8 afr[2][2];
    #pragma unroll
    for (int r = 0; r < 2; ++r) {
        const int s = s0 + wave * 32 + r * 16 + lrow;
        #pragma unroll
        for (int kk = 0; kk < 2; ++kk) {
            const float* xp = x + xbase + ((long)(kk * 32 + lk * 8) << 15) + s;
            #pragma unroll
            for (int i = 0; i < 8; ++i) {
                float v = xp[(long)i << 15];
                x2 += v * v;
                afr[r][kk][i] = f32_to_bf16_bits(v);
            }
        }
    }

    // ---- scan 512 codes; key = float_bits(d+16) low-9-bits-replaced-by-j ---
    unsigned key[2][4];
    #pragma unroll
    for (int r = 0; r < 2; ++r)
        #pragma unroll
        for (int q = 0; q < 4; ++q) key[r][q] = 0xFFFFFFFFu;

    const short8* ebv = (const short8*)ebf;
    #pragma unroll 2
    for (int jt = 0; jt < 32; ++jt) {
        const int j = jt * 16 + lrow;                 // this lane's code (B col)
        short8 b0 = ebv[j * 8 + lk];                  // channels [lk*8 .. +7]
        short8 b1 = ebv[j * 8 + 4 + lk];              // channels [32+lk*8 .. +7]
        float  en = eNorm16[j];
        float4v cinit = {en, en, en, en};             // bias folded into C
        #pragma unroll
        for (int r = 0; r < 2; ++r) {
            float4v acc = cinit;
            acc = __builtin_amdgcn_mfma_f32_16x16x32_bf16(afr[r][0], b0, acc, 0, 0, 0);
            acc = __builtin_amdgcn_mfma_f32_16x16x32_bf16(afr[r][1], b1, acc, 0, 0, 0);
            #pragma unroll
            for (int q = 0; q < 4; ++q) {
                unsigned u = (__float_as_uint(acc[q]) & 0xFFFFFE00u) | (unsigned)j;
                key[r][q] = min(key[r][q], u);
            }
        }
    }

    // ---- min butterfly across the 16 code-lanes ----------------------------
    #pragma unroll
    for (int r = 0; r < 2; ++r)
        #pragma unroll
        for (int q = 0; q < 4; ++q) {
            unsigned k = key[r][q];
            #pragma unroll
            for (int m = 1; m < 16; m <<= 1)
                k = min(k, (unsigned)__shfl_xor((int)k, m, 64));
            key[r][q] = k;
        }

    // ---- lrow==0 lanes own 8 rows: write idx, sum min distances ------------
    float smin = 0.0f;
    if (lrow == 0) {
        #pragma unroll
        for (int r = 0; r < 2; ++r) {
            ushort4v iv;
            #pragma unroll
            for (int q = 0; q < 4; ++q) {
                iv[q] = (unsigned short)(key[r][q] & 511u);
                smin += __uint_as_float(key[r][q] & 0xFFFFFE00u) - 16.0f;
            }
            *(ushort4v*)&idx_out[(long)b * SPATIAL + s0 + wave * 32 + r * 16 + lk * 4] = iv;
        }
    }
    float tot = x2 + smin;   // sum (q-x)^2 over wave rows = sum x^2 + sum d_min
    #pragma unroll
    for (int m = 32; m; m >>= 1) tot += __shfl_xor(tot, m, 64);
    if (lane == 0) red4[wave] = tot;
    __syncthreads();
    if (tid == 0) atomicAdd(loss_acc, red4[0] + red4[1] + red4[2] + red4[3]);
}

// ---------------- histogram: LDS bins, few global atomics -------------------
__global__ __launch_bounds__(256) void vq_hist(const unsigned short* __restrict__ idx,
                                               unsigned* __restrict__ counts) {
    __shared__ unsigned h[NCODES];
    const int tid = threadIdx.x;
    h[tid] = 0u; h[tid + 256] = 0u;
    __syncthreads();
    const unsigned* p = (const unsigned*)idx;          // 2 ushorts per load
    for (int i = blockIdx.x * 256 + tid; i < NROWS / 2; i += 64 * 256) {
        unsigned v = p[i];
        atomicAdd(&h[v & 0xFFFFu], 1u);
        atomicAdd(&h[v >> 16], 1u);
    }
    __syncthreads();
    atomicAdd(&counts[tid], h[tid]);
    atomicAdd(&counts[tid + 256], h[tid + 256]);
}

// ---------------- scatter: exact f32 codebook rows -> [C][S] output ---------
__global__ __launch_bounds__(256) void vq_scatter(const float* __restrict__ emb,
                                                  const unsigned short* __restrict__ idx,
                                                  float* __restrict__ out) {
    const int tid = threadIdx.x;
    const int blk = blockIdx.x;             // 1024 blocks
    const int b   = blk >> 7;
    const int s0  = (blk & 127) << 8;       // 256 spatial positions per block
    const int j   = idx[(long)b * SPATIAL + s0 + tid];
    const float4v* ep = (const float4v*)(emb + j * EDIM);
    const long obase = 1 + ((long)b << 21) + s0 + tid;
    #pragma unroll
    for (int cq = 0; cq < 16; ++cq) {
        float4v ev = ep[cq];                // emb[j][4cq..4cq+3], 16B L2 gather
        #pragma unroll
        for (int k = 0; k < 4; ++k)
            out[obase + ((long)(cq * 4 + k) << 15)] = ev[k];  // lane-contiguous
    }
}

// ---------------- final: scalars -------------------------------------------
__global__ void vq_final(const unsigned* __restrict__ counts,
                         const float* __restrict__ loss_acc,
                         float* __restrict__ out) {
    __shared__ float red[NCODES];
    int t = threadIdx.x;
    float p = (float)counts[t] * (1.0f / 262144.0f);
    red[t] = p * logf(p + 1e-10f);
    __syncthreads();
    for (int m = 256; m; m >>= 1) {
        if (t < m) red[t] += red[t + m];
        __syncthreads();
    }
    if (t == 0) {
        out[0]             = 1.25f * (*loss_acc) * (1.0f / 16777216.0f);
        out[1 + OUT_ELEMS] = expf(-red[0]);
    }
}

extern "C" void kernel_launch(void* const* d_in, const int* in_sizes, int n_in,
                              void* d_out, int out_size, void* d_ws, size_t ws_size,
                              hipStream_t stream) {
    const float* x   = (const float*)d_in[0];
    const float* emb = (const float*)d_in[1];
    float* out = (float*)d_out;

    char* ws = (char*)d_ws;
    float*          loss_acc = (float*)ws;                    // 4 B
    unsigned*       counts   = (unsigned*)(ws + 64);          // 2 KB
    float*          eNorm16  = (float*)(ws + 4096);           // 2 KB
    short*          ebf      = (short*)(ws + 8192);           // 64 KB bf16(-2e)
    unsigned short* idx      = (unsigned short*)(ws + 73728); // 512 KB indices

    vq_prep   <<<NCODES, 64, 0, stream>>>(emb, loss_acc, counts, eNorm16, ebf);
    vq_argmin <<<2048, 256, 0, stream>>>(x, eNorm16, ebf, idx, loss_acc);
    vq_hist   <<<64, 256, 0, stream>>>(idx, counts);
    vq_scatter<<<1024, 256, 0, stream>>>(emb, idx, out);
    vq_final  <<<1, 512, 0, stream>>>(counts, loss_acc, out);
}